// Round 14
// baseline (452.383 us; speedup 1.0000x reference)
//
#include <hip/hip_runtime.h>
#include <hip/hip_bf16.h>

// ---------------------------------------------------------------------------
// InterpretableMultiHeadAttention  (B=8, S=1024, D=1024, H=16, dk=64)
//   outputs [B,S,D] fp32 ; attn [B,Sq,H,Sk] fp32  (concatenated in d_out)
// Pipeline:
//   0) cvt     : q,k,Wq,Wk f32 -> bf16 (RNE)
//   1) proj_qk : m97-style global_load_lds GEMM (R13)
//   2) proj_v  : vsT = (v @ Wv^T)^T  bf16 [b][e][t]
//   3) attn    : REGISTER-DIRECT PV via permuted-K QK^T.
//                K-rows are fed to mfma(K,Q) in permuted order
//                perm_r=8*(r>>2)+(r&3) (+4 for 2nd sub-MFMA) so exp outputs
//                land exactly in the PV A-fragment layout (lane (g,r) holds
//                keys 8g..8g+7 of query r) -- no LDS P round-trip, no
//                lgkmcnt drains.  8 waves x 128 keys, pk[16]; LDS only for
//                l-reduce + heads reduce (34 KB) -> 3 blocks/CU = 24
//                waves/CU (was 16).  Plain (cached) attn stores: harness
//                memsets prove 6.8 TB/s write BW; NT never exceeded ~4.
//   4) out     : outputs = mean_h(heads) @ Wo^T
// R11 errata: vqk ablation was confounded by scratch spill (VGPR=64,
// 852MB phantom writes) -- its "441MB K over-fetch" conclusion was wrong.
// ---------------------------------------------------------------------------

typedef __attribute__((ext_vector_type(4))) float f32x4;
typedef __attribute__((ext_vector_type(8))) short bf16x8;
typedef __attribute__((ext_vector_type(4))) short short4v;
typedef __attribute__((ext_vector_type(4))) unsigned int uint4v;
typedef __attribute__((ext_vector_type(2))) unsigned int uint2v;

#define MFMA16(a, b, c) __builtin_amdgcn_mfma_f32_16x16x32_bf16((a), (b), (c), 0, 0, 0)

#define GLL16(gp, lp)                                                          \
  __builtin_amdgcn_global_load_lds(                                            \
      (const __attribute__((address_space(1))) void*)(gp),                     \
      (__attribute__((address_space(3))) void*)(lp), 16, 0, 0)

__device__ __forceinline__ unsigned int rne16(float f) {
  unsigned int u = __float_as_uint(f);
  return u + 0x7fffu + ((u >> 16) & 1u);   // round-to-nearest-even in bit 16
}
__device__ __forceinline__ unsigned int pack2bf(float a, float b) {
  return (rne16(a) >> 16) | (rne16(b) & 0xffff0000u);
}
__device__ __forceinline__ float bf2f(short s) {
  return __uint_as_float(((unsigned int)(unsigned short)s) << 16);
}
__device__ __forceinline__ float bflo(unsigned int u) {
  return __uint_as_float(u << 16);
}
__device__ __forceinline__ float bfhi(unsigned int u) {
  return __uint_as_float(u & 0xffff0000u);
}

// ---------------------------------------------------------------------------
// Kernel 0: f32 -> bf16 convert (q,k: 8M elems; Wq,Wk: 1M).  grid (4096, 4).
// ---------------------------------------------------------------------------
__global__ __launch_bounds__(256) void cvt_kernel(
    const float* __restrict__ q, const float* __restrict__ k,
    const float* __restrict__ Wq, const float* __restrict__ Wk,
    short* __restrict__ qb, short* __restrict__ kb,
    short* __restrict__ Wqb, short* __restrict__ Wkb)
{
  const int y = blockIdx.y;
  const float* src = (y == 0) ? q : (y == 1) ? k : (y == 2) ? Wq : Wk;
  short* dst = (y == 0) ? qb : (y == 1) ? kb : (y == 2) ? Wqb : Wkb;
  const int n = (y < 2) ? (8 * 1024 * 1024) : (1024 * 1024);
  const int i = (blockIdx.x * 256 + threadIdx.x) * 8;
  if (i >= n) return;
  const float4 a = *(const float4*)&src[i];
  const float4 b = *(const float4*)&src[i + 4];
  uint4v o = {pack2bf(a.x, a.y), pack2bf(a.z, a.w),
              pack2bf(b.x, b.y), pack2bf(b.z, b.w)};
  *(uint4v*)&dst[i] = o;
}

// ---------------------------------------------------------------------------
// Kernel 1: fused Q/K projection, m97-style (R13).  grid = (64, 16).
// ---------------------------------------------------------------------------
__global__ __launch_bounds__(256) void proj_qk_kernel(
    const short* __restrict__ qb, const short* __restrict__ kb,
    const short* __restrict__ Wqb, const short* __restrict__ Wkb,
    __hip_bfloat16* __restrict__ qs, __hip_bfloat16* __restrict__ ks)
{
  const int K = 1024, N = 1024;
  __shared__ short a_lds[128 * 32];
  __shared__ short b_lds[128 * 32];
  const int tid = threadIdx.x;
  const int lane = tid & 63, wid = tid >> 6;
  const int g = lane >> 4, r = lane & 15;
  const bool isK = blockIdx.y >= 8;
  const short* A = isK ? kb : qb;
  const short* W = isK ? Wkb : Wqb;
  __hip_bfloat16* C = isK ? ks : qs;
  const float scale = isK ? 1.0f : 0.125f;
  const int m0 = blockIdx.x * 128;
  const int n0 = (blockIdx.y & 7) * 128;
  const int wm = (wid >> 1) * 64, wn = (wid & 1) * 64;

  const int Ra = wid * 32;
  const int srow = lane >> 2, sslot = lane & 3;
  const long aoff0 = (long)(m0 + Ra + srow) * K + sslot * 8;
  const long aoff1 = (long)(m0 + Ra + 16 + srow) * K + sslot * 8;
  const long boff0 = (long)(n0 + Ra + srow) * K + sslot * 8;
  const long boff1 = (long)(n0 + Ra + 16 + srow) * K + sslot * 8;

  f32x4 acc[4][4];
#pragma unroll
  for (int i = 0; i < 4; ++i)
#pragma unroll
    for (int j = 0; j < 4; ++j) acc[i][j] = (f32x4){0.f, 0.f, 0.f, 0.f};

  for (int k0 = 0; k0 < K; k0 += 32) {
    __syncthreads();
    GLL16(A + aoff0 + k0, &a_lds[Ra * 32]);
    GLL16(A + aoff1 + k0, &a_lds[(Ra + 16) * 32]);
    GLL16(W + boff0 + k0, &b_lds[Ra * 32]);
    GLL16(W + boff1 + k0, &b_lds[(Ra + 16) * 32]);
    __syncthreads();
    bf16x8 af[4], bf[4];
#pragma unroll
    for (int t = 0; t < 4; ++t) {
      af[t] = *(bf16x8*)&a_lds[(wm + t * 16 + r) * 32 + g * 8];
      bf[t] = *(bf16x8*)&b_lds[(wn + t * 16 + r) * 32 + g * 8];
    }
#pragma unroll
    for (int mt = 0; mt < 4; ++mt)
#pragma unroll
      for (int nt = 0; nt < 4; ++nt)
        acc[mt][nt] = MFMA16(af[mt], bf[nt], acc[mt][nt]);
  }

#pragma unroll
  for (int mt = 0; mt < 4; ++mt)
#pragma unroll
    for (int nt = 0; nt < 4; ++nt) {
      const int n = n0 + wn + nt * 16 + r;
#pragma unroll
      for (int j = 0; j < 4; ++j) {
        const int m = m0 + wm + mt * 16 + 4 * g + j;
        C[m * N + n] = __float2bfloat16(acc[mt][nt][j] * scale);
      }
    }
}

// ---------------------------------------------------------------------------
// Kernel 2: V projection, output TRANSPOSED per batch: vsT[b][e][t] bf16.
// ---------------------------------------------------------------------------
__global__ __launch_bounds__(256) void proj_v_kernel(
    const float* __restrict__ vin, const float* __restrict__ Wv,
    __hip_bfloat16* __restrict__ vsT)
{
  const int K = 1024;
  __shared__ short a_lds[128][40];
  __shared__ short b_lds[64][40];
  const int tid  = threadIdx.x;
  const int lane = tid & 63, wid = tid >> 6;
  const int g = lane >> 4, r = lane & 15;
  const int m0 = blockIdx.x * 128;
  const int wm = wid * 32;
  const int lrow = tid >> 3, lcol = (tid & 7) * 4;

  f32x4 acc[2][4];
#pragma unroll
  for (int i = 0; i < 2; ++i)
#pragma unroll
    for (int j = 0; j < 4; ++j) acc[i][j] = (f32x4){0.f, 0.f, 0.f, 0.f};

  for (int k0 = 0; k0 < K; k0 += 32) {
    float4 av[4], wv2[2];
#pragma unroll
    for (int p = 0; p < 4; ++p)
      av[p] = *(const float4*)&vin[(m0 + lrow + p * 32) * K + k0 + lcol];
#pragma unroll
    for (int p = 0; p < 2; ++p)
      wv2[p] = *(const float4*)&Wv[(lrow + p * 32) * K + k0 + lcol];
    __syncthreads();
#pragma unroll
    for (int p = 0; p < 4; ++p) {
      uint2v ua = {pack2bf(av[p].x, av[p].y), pack2bf(av[p].z, av[p].w)};
      *(uint2v*)&a_lds[lrow + p * 32][lcol] = ua;
    }
#pragma unroll
    for (int p = 0; p < 2; ++p) {
      uint2v uw = {pack2bf(wv2[p].x, wv2[p].y), pack2bf(wv2[p].z, wv2[p].w)};
      *(uint2v*)&b_lds[lrow + p * 32][lcol] = uw;
    }
    __syncthreads();
    bf16x8 af[2], bf[4];
#pragma unroll
    for (int t = 0; t < 2; ++t) af[t] = *(bf16x8*)&a_lds[wm + t * 16 + r][g * 8];
#pragma unroll
    for (int t = 0; t < 4; ++t) bf[t] = *(bf16x8*)&b_lds[t * 16 + r][g * 8];
#pragma unroll
    for (int mt = 0; mt < 2; ++mt)
#pragma unroll
      for (int nt = 0; nt < 4; ++nt)
        acc[mt][nt] = MFMA16(af[mt], bf[nt], acc[mt][nt]);
  }

#pragma unroll
  for (int mt = 0; mt < 2; ++mt)
#pragma unroll
    for (int nt = 0; nt < 4; ++nt) {
      const int e = nt * 16 + r;
#pragma unroll
      for (int j = 0; j < 4; ++j) {
        const int m = m0 + wm + mt * 16 + 4 * g + j;
        const int b = m >> 10, t = m & 1023;
        vsT[b * 65536 + e * 1024 + t] = __float2bfloat16(acc[mt][nt][j]);
      }
    }
}

// ---------------------------------------------------------------------------
// Kernel 3: fused attention, register-direct PV.  grid = 8192 (XCD-swizzled),
// block = 512 (8 waves).  Wave kc owns 16 queries x keys [kc*128, +128).
//   QK: K-rows permuted (perm_r = 8*(r>>2)+(r&3), +4 for u=1) so output reg
//   j of sub-MFMA u = key 8g+4u+j -> pk[16] is ALREADY the PV A-fragment.
//   l: 2 shuffles -> l_lds[8][16] -> 1 barrier -> 8-way sum.
//   PV: {4 V loads, pa=bitcast(pk), 4 MFMA} x4 chunks, no LDS.
//   attn: plain f32x4 stores (2x16B = 32B contiguous/lane/chunk), lane's own
//   inv (P[q=r] is lane-resident).
//   heads: partials -> heads_lds[8][16][66] -> barrier -> distributed
//   8-way sum x2 cols/thread, scaled by inv_lds[row], bf16 pair store.
// ---------------------------------------------------------------------------
__global__ __launch_bounds__(512, 6) void attn_kernel(
    const __hip_bfloat16* __restrict__ qs_, const __hip_bfloat16* __restrict__ ks_,
    const __hip_bfloat16* __restrict__ vsT_, float* __restrict__ attn_out,
    __hip_bfloat16* __restrict__ heads_)
{
  const int S = 1024, H = 16;
  const int tid = threadIdx.x, lane = tid & 63, kc = tid >> 6;   // 8 waves
  const int g = lane >> 4, r = lane & 15;
  const int lin = ((int)blockIdx.x & 7) * 1024 + ((int)blockIdx.x >> 3);
  const int qb = lin & 63, h = (lin >> 6) & 15, b = lin >> 10;
  const int bh = b * H + h;
  const int qrow = qb * 16;

  __shared__ float heads_lds[8][16][66];   // 33.8 KB, stride 66 -> spread banks
  __shared__ float l_lds[8][16];
  __shared__ float inv_lds[16];

  const short* qsp = (const short*)qs_;
  const short* ksp = (const short*)ks_;
  const short* vsp = (const short*)vsT_;
  short* headsp = (short*)heads_;

  const int qidx = (b * S + qrow + r) * 1024 + h * 64;
  const bf16x8 qf0 = *(const bf16x8*)&qsp[qidx + g * 8];
  const bf16x8 qf1 = *(const bf16x8*)&qsp[qidx + 32 + g * 8];

  // permuted K base: key(r,c,u) = kc*128 + c*32 + 4u + perm_r
  const int perm_r = 8 * (r >> 2) + (r & 3);
  const int kpb = (b * S + kc * 128 + perm_r) * 1024 + h * 64 + g * 8;

  // ---- QK pass: exp(s) packed bf16 in pk[16], PV-fragment-ordered ----
  unsigned int pk[16];
  float lsa0 = 0.f, lsa1 = 0.f;
#pragma unroll
  for (int c = 0; c < 4; ++c) {
#pragma unroll
    for (int u = 0; u < 2; ++u) {
      const int ko = (c * 32 + 4 * u) * 1024;
      const bf16x8 klo = *(const bf16x8*)&ksp[kpb + ko];
      const bf16x8 khi = *(const bf16x8*)&ksp[kpb + ko + 32];
      f32x4 s = (f32x4){0.f, 0.f, 0.f, 0.f};
      s = MFMA16(klo, qf0, s);
      s = MFMA16(khi, qf1, s);
      const float e0 = __expf(s[0]), e1 = __expf(s[1]);
      const float e2 = __expf(s[2]), e3 = __expf(s[3]);
      pk[c * 4 + 2 * u]     = pack2bf(e0, e1);   // keys 8g+4u+0,1 of query r
      pk[c * 4 + 2 * u + 1] = pack2bf(e2, e3);   // keys 8g+4u+2,3
      if (u == 0) lsa0 += (e0 + e1) + (e2 + e3);
      else        lsa1 += (e0 + e1) + (e2 + e3);
    }
  }
  float ls = lsa0 + lsa1;
  ls += __shfl_xor(ls, 16);
  ls += __shfl_xor(ls, 32);          // sum over this wave's 128 keys
  if (g == 0) l_lds[kc][r] = ls;
  __syncthreads();                   // barrier 1 of 2
  const float lf = ((l_lds[0][r] + l_lds[1][r]) + (l_lds[2][r] + l_lds[3][r])) +
                   ((l_lds[4][r] + l_lds[5][r]) + (l_lds[6][r] + l_lds[7][r]));
  const float inv = 1.f / lf;        // normalizer for query r (lane-resident)
  if (kc == 0 && g == 0) inv_lds[r] = inv;

  // ---- PV directly from pk registers + attn stores ----
  f32x4 hacc[4];
#pragma unroll
  for (int i = 0; i < 4; ++i) hacc[i] = (f32x4){0.f, 0.f, 0.f, 0.f};
  const int vbase = b * 65536 + r * 1024 + g * 8 + kc * 128;
  const int arow = ((b * S + qrow + r) * H + h) * S + kc * 128;

#pragma unroll
  for (int c = 0; c < 4; ++c) {
    const int tcl = c * 32;
    bf16x8 vf[4];
#pragma unroll
    for (int nt = 0; nt < 4; ++nt)
      vf[nt] = *(const bf16x8*)&vsp[vbase + nt * 16384 + tcl];
    uint4v pu = {pk[4 * c + 0], pk[4 * c + 1], pk[4 * c + 2], pk[4 * c + 3]};
    const bf16x8 pa = __builtin_bit_cast(bf16x8, pu);
#pragma unroll
    for (int nt = 0; nt < 4; ++nt)
      hacc[nt] = MFMA16(pa, vf[nt], hacc[nt]);
    // attn row segment: keys tcl+8g..+7 of query r (32B contiguous)
    f32x4 o0, o1;
    o0[0] = bflo(pk[4 * c + 0]) * inv; o0[1] = bfhi(pk[4 * c + 0]) * inv;
    o0[2] = bflo(pk[4 * c + 1]) * inv; o0[3] = bfhi(pk[4 * c + 1]) * inv;
    o1[0] = bflo(pk[4 * c + 2]) * inv; o1[1] = bfhi(pk[4 * c + 2]) * inv;
    o1[2] = bflo(pk[4 * c + 3]) * inv; o1[3] = bfhi(pk[4 * c + 3]) * inv;
    *(f32x4*)&attn_out[arow + tcl + 8 * g] = o0;
    *(f32x4*)&attn_out[arow + tcl + 8 * g + 4] = o1;
  }

  // ---- heads partials; PV output query = ROW 4g+j ----
#pragma unroll
  for (int nt = 0; nt < 4; ++nt)
#pragma unroll
    for (int j = 0; j < 4; ++j)
      heads_lds[kc][4 * g + j][nt * 16 + r] = hacc[nt][j];
  __syncthreads();                   // barrier 2 of 2

  // ---- final: 8-way sum, 2 cols/thread, row-indexed normalizer ----
  {
    const int row = tid >> 5, c2 = (tid & 31) * 2;
    float s0 = 0.f, s1 = 0.f;
#pragma unroll
    for (int w = 0; w < 8; ++w) {
      s0 += heads_lds[w][row][c2];
      s1 += heads_lds[w][row][c2 + 1];
    }
    const float iv = inv_lds[row];
    const unsigned int o = pack2bf(s0 * iv, s1 * iv);
    *(unsigned int*)&headsp[(bh * S + qrow + row) * 64 + c2] = o;
  }
}

// ---------------------------------------------------------------------------
// Kernel 4: outputs = mean_h(heads) @ Wo^T.  grid = 512, 16 rows per block.
// ---------------------------------------------------------------------------
__global__ __launch_bounds__(256) void out_kernel(
    const __hip_bfloat16* __restrict__ heads_, const float* __restrict__ Wo,
    float* __restrict__ out)
{
  __shared__ float hm[16][64];
  const int tid = threadIdx.x;
  const int m0 = blockIdx.x * 16;
  const short* headsp = (const short*)heads_;

  {
    const int row = tid >> 4, e4 = (tid & 15) * 4;
    const int m = m0 + row, b = m >> 10, s = m & 1023;
    float a0 = 0.f, a1 = 0.f, a2 = 0.f, a3 = 0.f;
    for (int hh = 0; hh < 16; ++hh) {
      const short4v hv =
          *(const short4v*)&headsp[((b * 16 + hh) * 1024 + s) * 64 + e4];
      a0 += bf2f(hv[0]); a1 += bf2f(hv[1]); a2 += bf2f(hv[2]); a3 += bf2f(hv[3]);
    }
    const float sc = 1.f / 16.f;
    hm[row][e4 + 0] = a0 * sc; hm[row][e4 + 1] = a1 * sc;
    hm[row][e4 + 2] = a2 * sc; hm[row][e4 + 3] = a3 * sc;
  }
  __syncthreads();

  for (int c = 0; c < 4; ++c) {
    const int d = c * 256 + tid;
    float4 wo4[16];
#pragma unroll
    for (int i = 0; i < 16; ++i) wo4[i] = *(const float4*)&Wo[d * 64 + i * 4];
    for (int row = 0; row < 16; ++row) {
      float a = 0.f;
#pragma unroll
      for (int i = 0; i < 16; ++i) {
        const float4 h4 = *(const float4*)&hm[row][i * 4];
        a += h4.x * wo4[i].x + h4.y * wo4[i].y + h4.z * wo4[i].z + h4.w * wo4[i].w;
      }
      out[(m0 + row) * 1024 + d] = a;
    }
  }
}

// ---------------------------------------------------------------------------
extern "C" void kernel_launch(void* const* d_in, const int* in_sizes, int n_in,
                              void* d_out, int out_size, void* d_ws, size_t ws_size,
                              hipStream_t stream) {
  const float* q  = (const float*)d_in[0];
  const float* k  = (const float*)d_in[1];
  const float* v  = (const float*)d_in[2];
  const float* Wq = (const float*)d_in[3];
  const float* Wk = (const float*)d_in[4];
  const float* Wv = (const float*)d_in[5];
  const float* Wo = (const float*)d_in[6];

  float* out0 = (float*)d_out;                       // [8,1024,1024]
  float* attn = out0 + (size_t)8 * 1024 * 1024;      // [8,1024,16,1024]

  char* ws = (char*)d_ws;
  __hip_bfloat16* qs    = (__hip_bfloat16*)(ws);                     // 16 MB
  __hip_bfloat16* ksbuf = (__hip_bfloat16*)(ws + (16u << 20));       // 16 MB
  __hip_bfloat16* vsT   = (__hip_bfloat16*)(ws + (32u << 20));       //  1 MB
  __hip_bfloat16* heads = (__hip_bfloat16*)(ws + (33u << 20));       // 16 MB
  // converted bf16 inputs: qbuf ALIASES heads (dead until attn writes it;
  // qbuf fully consumed by proj_qk before attn runs -- stream ordered)
  short* qbuf  = (short*)(ws + (33u << 20));                         // 16 MB
  short* kbuf  = (short*)(ws + (49u << 20));                         // 16 MB
  short* Wqbuf = (short*)(ws + (65u << 20));                         //  2 MB
  short* Wkbuf = (short*)(ws + (67u << 20));                         //  2 MB

  dim3 blk(256);
  cvt_kernel<<<dim3(4096, 4), blk, 0, stream>>>(q, k, Wq, Wk,
                                                qbuf, kbuf, Wqbuf, Wkbuf);
  proj_qk_kernel<<<dim3(64, 16), blk, 0, stream>>>(qbuf, kbuf, Wqbuf, Wkbuf,
                                                   qs, ksbuf);
  proj_v_kernel<<<dim3(64), blk, 0, stream>>>(v, Wv, vsT);
  attn_kernel<<<dim3(8192), dim3(512), 0, stream>>>(qs, ksbuf, vsT, attn, heads);
  out_kernel<<<dim3(512), blk, 0, stream>>>(heads, Wo, out0);
}